// Round 17
// baseline (181.358 us; speedup 1.0000x reference)
//
#include <hip/hip_runtime.h>
#include <hip/hip_bf16.h>
#include <cstdint>

// Problem constants (from reference): B=4, T=2048, D=512, FF=2048, E=8, K=2
#define NTOK   8192      // B*T
#define DDIM   512
#define FDIM   2048
#define NEXP   8
#define NSLOT  16384     // 2*NTOK assignments (top-2, always exactly 2 per token)
#define MAXTILES 136     // sum_e ceil(cnt_e/128) <= 16384/128 + 8

typedef __bf16 bf16;
typedef __bf16 bf16x8 __attribute__((ext_vector_type(8)));
typedef float  f32x4  __attribute__((ext_vector_type(4)));

typedef uint32_t __attribute__((address_space(1))) gu32;
typedef uint32_t __attribute__((address_space(3))) lu32;

// async global->LDS, 16B per lane; LDS dest must be wave-uniform base (+lane*16 implicit)
__device__ __forceinline__ void gload16(const void* g, void* l) {
    __builtin_amdgcn_global_load_lds((const gu32*)(uintptr_t)g,
                                     (lu32*)(uintptr_t)l, 16, 0, 0);
}

// ---------------- prep: gating + both weight transposes, one launch -------------
// blocks [0,1024):      gating (logits -> softmax -> top2 -> weights; x -> bf16)
// blocks [1024,3072):   W1 fp32 [E][D][FF] -> bf16 [E][FF][D]
// blocks [3072,5120):   W2 fp32 [E][FF][D] -> bf16 [E][D][FF]
__global__ __launch_bounds__(256)
void prep_kernel(const float* __restrict__ x, const float* __restrict__ Wg,
                 const float* __restrict__ bg, bf16* __restrict__ xb,
                 int* __restrict__ top_idx, float* __restrict__ top_w,
                 int* __restrict__ counts,
                 const float* __restrict__ W1, bf16* __restrict__ w1t,
                 const float* __restrict__ W2, bf16* __restrict__ w2t)
{
    const int bid = blockIdx.x;
    if (bid < 1024) {
        // ---------------- gating (proven body, 1024 blocks) ------------------
        __shared__ int cnt_s[NEXP];
        if (threadIdx.x < NEXP) cnt_s[threadIdx.x] = 0;
        __syncthreads();

        const int w = threadIdx.x >> 6;
        const int l = threadIdx.x & 63;
        const int gw = bid * 4 + w;   // 4096 waves

        for (int n = gw; n < NTOK; n += 4096) {
            const float4* xp = (const float4*)(x + (size_t)n * DDIM + l * 8);
            float4 x0 = xp[0], x1 = xp[1];
            float xf[8] = {x0.x, x0.y, x0.z, x0.w, x1.x, x1.y, x1.z, x1.w};

            bf16x8 xv;
#pragma unroll
            for (int i = 0; i < 8; ++i) xv[i] = (bf16)xf[i];
            *(bf16x8*)(xb + (size_t)n * DDIM + l * 8) = xv;

            float acc[8] = {0.f,0.f,0.f,0.f,0.f,0.f,0.f,0.f};
#pragma unroll
            for (int i = 0; i < 8; ++i) {
                const float4* wp = (const float4*)(Wg + (size_t)(l * 8 + i) * NEXP);
                float4 wa = wp[0], wb = wp[1];
                acc[0] += xf[i] * wa.x; acc[1] += xf[i] * wa.y;
                acc[2] += xf[i] * wa.z; acc[3] += xf[i] * wa.w;
                acc[4] += xf[i] * wb.x; acc[5] += xf[i] * wb.y;
                acc[6] += xf[i] * wb.z; acc[7] += xf[i] * wb.w;
            }
#pragma unroll
            for (int m = 32; m >= 1; m >>= 1)
#pragma unroll
                for (int e = 0; e < 8; ++e)
                    acc[e] += __shfl_xor(acc[e], m);

            if (l == 0) {
                float logit[8];
#pragma unroll
                for (int e = 0; e < 8; ++e) logit[e] = acc[e] + bg[e];
                float mx = logit[0];
#pragma unroll
                for (int e = 1; e < 8; ++e) mx = fmaxf(mx, logit[e]);
                float g[8], s = 0.f;
#pragma unroll
                for (int e = 0; e < 8; ++e) { g[e] = expf(logit[e] - mx); s += g[e]; }
                float inv = 1.f / s;
#pragma unroll
                for (int e = 0; e < 8; ++e) g[e] *= inv;
                // top-2, ties -> lower index first (matches lax.top_k)
                int e0 = 0;
#pragma unroll
                for (int e = 1; e < 8; ++e) if (g[e] > g[e0]) e0 = e;
                int e1 = (e0 == 0) ? 1 : 0;
#pragma unroll
                for (int e = 0; e < 8; ++e) if (e != e0 && e != e1 && g[e] > g[e1]) e1 = e;
                float denom = g[e0] + g[e1] + 0.01f;
                top_idx[n * 2 + 0] = e0;
                top_idx[n * 2 + 1] = e1;
                top_w[n * 2 + 0] = g[e0] / denom;
                top_w[n * 2 + 1] = g[e1] / denom;
                atomicAdd(&cnt_s[e0], 1);
                atomicAdd(&cnt_s[e1], 1);
            }
        }
        __syncthreads();
        if (threadIdx.x < NEXP) atomicAdd(&counts[threadIdx.x], cnt_s[threadIdx.x]);
    } else {
        // ---------------- transpose+convert (proven body) --------------------
        const float* src; bf16* dst; int R, C, bx, by, bz;
        if (bid < 3072) {
            const int idx = bid - 1024;              // grid (32, 8, 8)
            src = W1; dst = w1t; R = DDIM; C = FDIM;
            bx = idx & 31; by = (idx >> 5) & 7; bz = idx >> 8;
        } else {
            const int idx = bid - 3072;              // grid (8, 32, 8)
            src = W2; dst = w2t; R = FDIM; C = DDIM;
            bx = idx & 7; by = (idx >> 3) & 31; bz = idx >> 8;
        }
        __shared__ bf16 tile[64][72];   // 72 = 16B-aligned row stride, rotates banks
        const size_t eo = (size_t)bz * R * C;
        src += eo; dst += eo;
        const int c0 = bx * 64, r0 = by * 64;
        const int tq = (threadIdx.x & 15) * 4;   // col quad within 64
        const int tr = threadIdx.x >> 4;         // 16 rows per pass
#pragma unroll
        for (int j = 0; j < 4; ++j) {
            const int r = tr + j * 16;
            float4 v = *(const float4*)(src + (size_t)(r0 + r) * C + c0 + tq);
            tile[tq + 0][r] = (bf16)v.x;
            tile[tq + 1][r] = (bf16)v.y;
            tile[tq + 2][r] = (bf16)v.z;
            tile[tq + 3][r] = (bf16)v.w;
        }
        __syncthreads();
        const int x8 = (threadIdx.x & 7) * 8;    // 8 bf16 = 16B per store
        const int cr = threadIdx.x >> 3;         // 32 rows per pass
#pragma unroll
        for (int j = 0; j < 2; ++j) {
            const int c = cr + j * 32;
            *(bf16x8*)(dst + (size_t)(c0 + c) * R + r0 + x8) = *(const bf16x8*)&tile[c][x8];
        }
    }
}

// ---------------- scatter: offsets computed in-register ------------------------
__global__ __launch_bounds__(256)
void scatter_kernel(const int* __restrict__ top_idx, const float* __restrict__ top_w,
                    const int* __restrict__ counts, int* __restrict__ cursors,
                    int* __restrict__ slot_tok, float* __restrict__ slot_w,
                    int* __restrict__ pos)
{
    __shared__ int lcnt[NEXP];
    __shared__ int lbase[NEXP];
    __shared__ int offs_s[NEXP];
    const int t = threadIdx.x;
    if (t < NEXP) lcnt[t] = 0;
    if (t == 0) {
        int off = 0;
#pragma unroll
        for (int e = 0; e < NEXP; ++e) { offs_s[e] = off; off += counts[e]; }
    }
    __syncthreads();
    const int n = blockIdx.x * 256 + t;   // NTOK = 32*256 exactly
    const int e0 = top_idx[n * 2 + 0];
    const int e1 = top_idx[n * 2 + 1];
    const int r0 = atomicAdd(&lcnt[e0], 1);
    const int r1 = atomicAdd(&lcnt[e1], 1);
    __syncthreads();
    if (t < NEXP) lbase[t] = atomicAdd(&cursors[t], lcnt[t]);
    __syncthreads();
    const int s0 = offs_s[e0] + lbase[e0] + r0;
    const int s1 = offs_s[e1] + lbase[e1] + r1;
    slot_tok[s0] = n; slot_w[s0] = top_w[n * 2 + 0]; pos[n * 2 + 0] = s0;
    slot_tok[s1] = n; slot_w[s1] = top_w[n * 2 + 1]; pos[n * 2 + 1] = s1;
}

// ---------------- grouped GEMM: m97 wave shape + R13 1-barrier loop + T2 --------
// C[slot, n] = A[slot, :KD] * B_e[n, :KD]^T
// FIRST:  A = xb (via slot_tok indirection), B = w1t, Out = Hg (bias+relu+bf16)
// !FIRST: A = Hg (direct slot rows),         B = w2t, Out = Yg (bias, bf16)
// 256 threads = 4 waves (2x2 wave grid, 64x64 per wave, acc[4][4], 16 MFMA /
// 8 ds_read per K-step). 32KB dbuf -> 4-5 blocks/CU of INDEPENDENT 4-wave
// barrier convoys (vs R16's 8-wave convoys) — m97's 740 cyc/block-iter shape.
// K-loop: issue next-tile STAGE at top, compute current, ONE __syncthreads.
// T2 swizzle kept (row-mod-8 invariants unchanged: wm*64 == 0 mod 8).
// Tile map decoded per block from counts[8].
template<int KD, int ND, bool FIRST>
__global__ __launch_bounds__(256)
void moe_gemm(const bf16* __restrict__ Adata, const bf16* __restrict__ Bt,
              const float* __restrict__ bias, bf16* __restrict__ Out,
              const int* __restrict__ slot_tok, const int* __restrict__ counts)
{
    constexpr int NX  = ND / 128;          // N-tiles: 16 (GEMM1) or 4 (GEMM2)
    constexpr int NWG = NX * MAXTILES;     // 2176 / 544 — both % 8 == 0
    constexpr int Q   = NWG / 8;
    constexpr int NT  = KD / 32;           // K-tiles: 16 (GEMM1) or 64 (GEMM2)

    const int orig = blockIdx.y * NX + blockIdx.x;       // HW dispatch order
    const int work = (orig & 7) * Q + (orig >> 3);       // bijective XCD chunking
    const int wy   = work / NX;                          // row-tile
    const int wx   = work - wy * NX;                     // N-tile (fastest: shares A)

    // decode (e, rt, row0, rowEnd) from counts
    int cnt[NEXP];
#pragma unroll
    for (int ee = 0; ee < NEXP; ++ee) cnt[ee] = counts[ee];
    int e = -1, rt = 0, row0 = 0, rowEnd = 0, rem = wy, off = 0;
#pragma unroll
    for (int ee = 0; ee < NEXP; ++ee) {
        const int nt = (cnt[ee] + 127) >> 7;
        if (e < 0 && rem < nt) { e = ee; rt = rem; row0 = off + rt * 128; rowEnd = off + cnt[ee]; }
        if (e < 0) rem -= nt;
        off += cnt[ee];
    }
    if (e < 0) return;   // wy >= ntiles

    const int nb = wx * 128;

    // double-buffered LDS: [2] x 128x32 bf16 for A and B  (32KB total)
    __shared__ __align__(16) bf16 As[2 * 128 * 32];
    __shared__ __align__(16) bf16 Bs[2 * 128 * 32];

    const int t = threadIdx.x;
    const int w = t >> 6, l = t & 63;      // 4 waves
    const int wm = w >> 1, wn = w & 1;     // 2x2 wave grid, 64x64 per wave

    // staging: 2 rounds/matrix; round j covers rows j*64 + (t>>2), phys slot t&3.
    // T2: source k-slot pre-swizzled = (t&3) ^ ((row>>1)&3); (row>>1)&3 == (t>>3)&3.
    const int colb = (((t & 3) ^ ((t >> 3) & 3)) * 8);

    const bf16* aSrcJ[2];
    const bf16* bSrcJ[2];
#pragma unroll
    for (int j = 0; j < 2; ++j) {
        const int r = j * 64 + (t >> 2);
        int sr = row0 + r; if (sr >= NSLOT) sr = NSLOT - 1;
        if (FIRST) aSrcJ[j] = Adata + (size_t)slot_tok[sr] * KD + colb;
        else       aSrcJ[j] = Adata + (size_t)sr * KD + colb;
        bSrcJ[j] = Bt + ((size_t)e * ND + nb + r) * KD + colb;
    }

    f32x4 acc[4][4] = {};
    const int lr = l & 15;
    // T2 read-side: phys slot = (l>>4) ^ ((lr>>1)&3)
    const int lks = (((l >> 4) ^ ((lr >> 1) & 3)) * 8);

    auto STAGE = [&](int buf, int k0) {
        // LDS dest: wave-uniform base + implicit lane*16B; elem off j*2048 + t*8
#pragma unroll
        for (int j = 0; j < 2; ++j) {
            gload16(aSrcJ[j] + k0, As + buf * 4096 + j * 2048 + w * 512);
            gload16(bSrcJ[j] + k0, Bs + buf * 4096 + j * 2048 + w * 512);
        }
    };
    auto COMPUTE = [&](int buf) {
        const bf16* ab = As + buf * 4096;
        const bf16* bb = Bs + buf * 4096;
        bf16x8 aF[4], bF[4];
#pragma unroll
        for (int mi = 0; mi < 4; ++mi)
            aF[mi] = *(const bf16x8*)(ab + (wm * 64 + mi * 16 + lr) * 32 + lks);
#pragma unroll
        for (int nj = 0; nj < 4; ++nj)
            bF[nj] = *(const bf16x8*)(bb + (wn * 64 + nj * 16 + lr) * 32 + lks);
#pragma unroll
        for (int mi = 0; mi < 4; ++mi)
#pragma unroll
            for (int nj = 0; nj < 4; ++nj)
                acc[mi][nj] = __builtin_amdgcn_mfma_f32_16x16x32_bf16(
                    aF[mi], bF[nj], acc[mi][nj], 0, 0, 0);
    };

    // prologue: tile 0 staged and drained (compiler emits waits at the barrier)
    STAGE(0, 0);
    __syncthreads();

    int buf = 0;
    for (int t2 = 0; t2 < NT - 1; ++t2) {
        STAGE(buf ^ 1, (t2 + 1) * 32);   // issue next tile's loads first
        COMPUTE(buf);                     // ds_read + MFMA on current tile
        __syncthreads();                  // one barrier: drains loads, WAR-safe
        buf ^= 1;
    }
    COMPUTE(buf);                         // last tile (already drained)

    const int rowW = row0 + wm * 64;
    const int colW = nb + wn * 64;
#pragma unroll
    for (int mi = 0; mi < 4; ++mi) {
#pragma unroll
        for (int nj = 0; nj < 4; ++nj) {
#pragma unroll
            for (int r = 0; r < 4; ++r) {
                int row = rowW + mi * 16 + (l >> 4) * 4 + r;
                int col = colW + nj * 16 + lr;
                if (row < rowEnd) {
                    float v = acc[mi][nj][r] + bias[e * ND + col];
                    if (FIRST) v = fmaxf(v, 0.f);
                    Out[(size_t)row * ND + col] = (bf16)v;
                }
            }
        }
    }
}

// ---------------- combine: out[n] = w0*Y[slot0] + w1*Y[slot1] (bf16 Y) ----------
__global__ __launch_bounds__(256)
void combine_kernel(const bf16* __restrict__ Yg, const int* __restrict__ pos,
                    const float* __restrict__ slot_w, float* __restrict__ out)
{
    const int idx = blockIdx.x * 256 + threadIdx.x;  // over NTOK*DDIM/8
    const int n  = idx >> 6;                          // DDIM/8 = 64
    const int d8 = (idx & 63) * 8;
    const int s0 = pos[n * 2 + 0], s1 = pos[n * 2 + 1];
    const float w0 = slot_w[s0], w1 = slot_w[s1];
    bf16x8 a = *(const bf16x8*)(Yg + (size_t)s0 * DDIM + d8);
    bf16x8 b = *(const bf16x8*)(Yg + (size_t)s1 * DDIM + d8);
    float o[8];
#pragma unroll
    for (int j = 0; j < 8; ++j)
        o[j] = w0 * (float)a[j] + w1 * (float)b[j];
    float* op = out + (size_t)n * DDIM + d8;
    *(float4*)(op + 0) = make_float4(o[0], o[1], o[2], o[3]);
    *(float4*)(op + 4) = make_float4(o[4], o[5], o[6], o[7]);
}

extern "C" void kernel_launch(void* const* d_in, const int* in_sizes, int n_in,
                              void* d_out, int out_size, void* d_ws, size_t ws_size,
                              hipStream_t stream)
{
    (void)in_sizes; (void)n_in;
    const float* x  = (const float*)d_in[0];
    const float* Wg = (const float*)d_in[1];
    const float* bg = (const float*)d_in[2];
    const float* W1 = (const float*)d_in[3];
    const float* b1 = (const float*)d_in[4];
    const float* W2 = (const float*)d_in[5];
    const float* b2 = (const float*)d_in[6];
    float* out = (float*)d_out;

    uint8_t* ws = (uint8_t*)d_ws;
    size_t off = 0;
    auto alloc = [&](size_t bytes) -> void* {
        void* p = ws + off;
        off = (off + bytes + 255) & ~(size_t)255;
        return p;
    };
    bf16*  xb      = (bf16*)alloc((size_t)NTOK * DDIM * 2);
    bf16*  w1t     = (bf16*)alloc((size_t)NEXP * FDIM * DDIM * 2);  // [E][FF][D]
    bf16*  w2t     = (bf16*)alloc((size_t)NEXP * DDIM * FDIM * 2);  // [E][D][FF]
    bf16*  Hg      = (bf16*)alloc((size_t)NSLOT * FDIM * 2);
    bf16*  Yg      = (bf16*)alloc((size_t)NSLOT * DDIM * 2);
    int*   counts  = (int*)alloc(16 * 4);          // counts[0..7] + cursors[8..15]
    int*   cursors = counts + NEXP;                // same 64B memset covers both
    int*   top_idx = (int*)alloc((size_t)NTOK * 2 * 4);
    float* top_w   = (float*)alloc((size_t)NTOK * 2 * 4);
    int*   pos     = (int*)alloc((size_t)NTOK * 2 * 4);
    int*   slot_tok= (int*)alloc((size_t)NSLOT * 4);
    float* slot_w  = (float*)alloc((size_t)NSLOT * 4);

    if (ws_size < off) {
        // workspace too small: distinguishable failure signature (out = 0)
        hipMemsetAsync(d_out, 0, (size_t)out_size * 4, stream);
        return;
    }

    hipMemsetAsync(counts, 0, 16 * 4, stream);   // zero counts + cursors

    prep_kernel<<<5120, 256, 0, stream>>>(x, Wg, bg, xb, top_idx, top_w, counts,
                                          W1, w1t, W2, w2t);
    scatter_kernel<<<NTOK / 256, 256, 0, stream>>>(top_idx, top_w, counts, cursors,
                                                   slot_tok, slot_w, pos);

    moe_gemm<DDIM, FDIM, true><<<dim3(FDIM / 128, MAXTILES), 256, 0, stream>>>(
        xb, w1t, b1, Hg, slot_tok, counts);
    moe_gemm<FDIM, DDIM, false><<<dim3(DDIM / 128, MAXTILES), 256, 0, stream>>>(
        Hg, w2t, b2, Yg, slot_tok, counts);

    combine_kernel<<<(NTOK * DDIM / 8) / 256, 256, 0, stream>>>(Yg, pos, slot_w, out);
}

// Round 18
// 164.442 us; speedup vs baseline: 1.1029x; 1.1029x over previous
//
#include <hip/hip_runtime.h>
#include <hip/hip_bf16.h>
#include <cstdint>

// Problem constants (from reference): B=4, T=2048, D=512, FF=2048, E=8, K=2
#define NTOK   8192      // B*T
#define DDIM   512
#define FDIM   2048
#define NEXP   8
#define NSLOT  16384     // 2*NTOK assignments (top-2, always exactly 2 per token)
#define MAXTILES 136     // sum_e ceil(cnt_e/128) <= 16384/128 + 8

typedef __bf16 bf16;
typedef __bf16 bf16x8 __attribute__((ext_vector_type(8)));
typedef float  f32x4  __attribute__((ext_vector_type(4)));

typedef uint32_t __attribute__((address_space(1))) gu32;
typedef uint32_t __attribute__((address_space(3))) lu32;

// async global->LDS, 16B per lane; LDS dest must be wave-uniform base (+lane*16 implicit)
__device__ __forceinline__ void gload16(const void* g, void* l) {
    __builtin_amdgcn_global_load_lds((const gu32*)(uintptr_t)g,
                                     (lu32*)(uintptr_t)l, 16, 0, 0);
}

// ---------------- prep: gating + both weight transposes, one launch -------------
// blocks [0,1024):      gating (logits -> softmax -> top2 -> weights; x -> bf16)
// blocks [1024,3072):   W1 fp32 [E][D][FF] -> bf16 [E][FF][D]
// blocks [3072,5120):   W2 fp32 [E][FF][D] -> bf16 [E][D][FF]
__global__ __launch_bounds__(256)
void prep_kernel(const float* __restrict__ x, const float* __restrict__ Wg,
                 const float* __restrict__ bg, bf16* __restrict__ xb,
                 int* __restrict__ top_idx, float* __restrict__ top_w,
                 int* __restrict__ counts,
                 const float* __restrict__ W1, bf16* __restrict__ w1t,
                 const float* __restrict__ W2, bf16* __restrict__ w2t)
{
    const int bid = blockIdx.x;
    if (bid < 1024) {
        // ---------------- gating (proven body, 1024 blocks) ------------------
        __shared__ int cnt_s[NEXP];
        if (threadIdx.x < NEXP) cnt_s[threadIdx.x] = 0;
        __syncthreads();

        const int w = threadIdx.x >> 6;
        const int l = threadIdx.x & 63;
        const int gw = bid * 4 + w;   // 4096 waves

        for (int n = gw; n < NTOK; n += 4096) {
            const float4* xp = (const float4*)(x + (size_t)n * DDIM + l * 8);
            float4 x0 = xp[0], x1 = xp[1];
            float xf[8] = {x0.x, x0.y, x0.z, x0.w, x1.x, x1.y, x1.z, x1.w};

            bf16x8 xv;
#pragma unroll
            for (int i = 0; i < 8; ++i) xv[i] = (bf16)xf[i];
            *(bf16x8*)(xb + (size_t)n * DDIM + l * 8) = xv;

            float acc[8] = {0.f,0.f,0.f,0.f,0.f,0.f,0.f,0.f};
#pragma unroll
            for (int i = 0; i < 8; ++i) {
                const float4* wp = (const float4*)(Wg + (size_t)(l * 8 + i) * NEXP);
                float4 wa = wp[0], wb = wp[1];
                acc[0] += xf[i] * wa.x; acc[1] += xf[i] * wa.y;
                acc[2] += xf[i] * wa.z; acc[3] += xf[i] * wa.w;
                acc[4] += xf[i] * wb.x; acc[5] += xf[i] * wb.y;
                acc[6] += xf[i] * wb.z; acc[7] += xf[i] * wb.w;
            }
#pragma unroll
            for (int m = 32; m >= 1; m >>= 1)
#pragma unroll
                for (int e = 0; e < 8; ++e)
                    acc[e] += __shfl_xor(acc[e], m);

            if (l == 0) {
                float logit[8];
#pragma unroll
                for (int e = 0; e < 8; ++e) logit[e] = acc[e] + bg[e];
                float mx = logit[0];
#pragma unroll
                for (int e = 1; e < 8; ++e) mx = fmaxf(mx, logit[e]);
                float g[8], s = 0.f;
#pragma unroll
                for (int e = 0; e < 8; ++e) { g[e] = expf(logit[e] - mx); s += g[e]; }
                float inv = 1.f / s;
#pragma unroll
                for (int e = 0; e < 8; ++e) g[e] *= inv;
                // top-2, ties -> lower index first (matches lax.top_k)
                int e0 = 0;
#pragma unroll
                for (int e = 1; e < 8; ++e) if (g[e] > g[e0]) e0 = e;
                int e1 = (e0 == 0) ? 1 : 0;
#pragma unroll
                for (int e = 0; e < 8; ++e) if (e != e0 && e != e1 && g[e] > g[e1]) e1 = e;
                float denom = g[e0] + g[e1] + 0.01f;
                top_idx[n * 2 + 0] = e0;
                top_idx[n * 2 + 1] = e1;
                top_w[n * 2 + 0] = g[e0] / denom;
                top_w[n * 2 + 1] = g[e1] / denom;
                atomicAdd(&cnt_s[e0], 1);
                atomicAdd(&cnt_s[e1], 1);
            }
        }
        __syncthreads();
        if (threadIdx.x < NEXP) atomicAdd(&counts[threadIdx.x], cnt_s[threadIdx.x]);
    } else {
        // ---------------- transpose+convert (proven body) --------------------
        const float* src; bf16* dst; int R, C, bx, by, bz;
        if (bid < 3072) {
            const int idx = bid - 1024;              // grid (32, 8, 8)
            src = W1; dst = w1t; R = DDIM; C = FDIM;
            bx = idx & 31; by = (idx >> 5) & 7; bz = idx >> 8;
        } else {
            const int idx = bid - 3072;              // grid (8, 32, 8)
            src = W2; dst = w2t; R = FDIM; C = DDIM;
            bx = idx & 7; by = (idx >> 3) & 31; bz = idx >> 8;
        }
        __shared__ bf16 tile[64][72];   // 72 = 16B-aligned row stride, rotates banks
        const size_t eo = (size_t)bz * R * C;
        src += eo; dst += eo;
        const int c0 = bx * 64, r0 = by * 64;
        const int tq = (threadIdx.x & 15) * 4;   // col quad within 64
        const int tr = threadIdx.x >> 4;         // 16 rows per pass
#pragma unroll
        for (int j = 0; j < 4; ++j) {
            const int r = tr + j * 16;
            float4 v = *(const float4*)(src + (size_t)(r0 + r) * C + c0 + tq);
            tile[tq + 0][r] = (bf16)v.x;
            tile[tq + 1][r] = (bf16)v.y;
            tile[tq + 2][r] = (bf16)v.z;
            tile[tq + 3][r] = (bf16)v.w;
        }
        __syncthreads();
        const int x8 = (threadIdx.x & 7) * 8;    // 8 bf16 = 16B per store
        const int cr = threadIdx.x >> 3;         // 32 rows per pass
#pragma unroll
        for (int j = 0; j < 2; ++j) {
            const int c = cr + j * 32;
            *(bf16x8*)(dst + (size_t)(c0 + c) * R + r0 + x8) = *(const bf16x8*)&tile[c][x8];
        }
    }
}

// ---------------- scatter: offsets computed in-register ------------------------
__global__ __launch_bounds__(256)
void scatter_kernel(const int* __restrict__ top_idx, const float* __restrict__ top_w,
                    const int* __restrict__ counts, int* __restrict__ cursors,
                    int* __restrict__ slot_tok, float* __restrict__ slot_w,
                    int* __restrict__ pos)
{
    __shared__ int lcnt[NEXP];
    __shared__ int lbase[NEXP];
    __shared__ int offs_s[NEXP];
    const int t = threadIdx.x;
    if (t < NEXP) lcnt[t] = 0;
    if (t == 0) {
        int off = 0;
#pragma unroll
        for (int e = 0; e < NEXP; ++e) { offs_s[e] = off; off += counts[e]; }
    }
    __syncthreads();
    const int n = blockIdx.x * 256 + t;   // NTOK = 32*256 exactly
    const int e0 = top_idx[n * 2 + 0];
    const int e1 = top_idx[n * 2 + 1];
    const int r0 = atomicAdd(&lcnt[e0], 1);
    const int r1 = atomicAdd(&lcnt[e1], 1);
    __syncthreads();
    if (t < NEXP) lbase[t] = atomicAdd(&cursors[t], lcnt[t]);
    __syncthreads();
    const int s0 = offs_s[e0] + lbase[e0] + r0;
    const int s1 = offs_s[e1] + lbase[e1] + r1;
    slot_tok[s0] = n; slot_w[s0] = top_w[n * 2 + 0]; pos[n * 2 + 0] = s0;
    slot_tok[s1] = n; slot_w[s1] = top_w[n * 2 + 1]; pos[n * 2 + 1] = s1;
}

// ---------------- grouped GEMM: R13/R16 structure (best measured) ---------------
// C[slot, n] = A[slot, :KD] * B_e[n, :KD]^T
// FIRST:  A = xb (via slot_tok indirection), B = w1t, Out = Hg (bias+relu+bf16)
// !FIRST: A = Hg (direct slot rows),         B = w2t, Out = Yg (bias, bf16)
// 512 threads = 8 waves (4x2 wave grid, 32x64 per wave); 32KB dbuf -> ~5 blocks/CU.
// K-loop: issue next-tile STAGE at top, compute current, ONE __syncthreads.
// T2 swizzle (conflicts = 0, verified R12); XCD-bijective work remap;
// tile map decoded per block from counts[8] (scan kernel eliminated).
template<int KD, int ND, bool FIRST>
__global__ __launch_bounds__(512)
void moe_gemm(const bf16* __restrict__ Adata, const bf16* __restrict__ Bt,
              const float* __restrict__ bias, bf16* __restrict__ Out,
              const int* __restrict__ slot_tok, const int* __restrict__ counts)
{
    constexpr int NX  = ND / 128;          // N-tiles: 16 (GEMM1) or 4 (GEMM2)
    constexpr int NWG = NX * MAXTILES;     // 2176 / 544 — both % 8 == 0
    constexpr int Q   = NWG / 8;
    constexpr int NT  = KD / 32;           // K-tiles: 16 (GEMM1) or 64 (GEMM2)

    const int orig = blockIdx.y * NX + blockIdx.x;       // HW dispatch order
    const int work = (orig & 7) * Q + (orig >> 3);       // bijective XCD chunking
    const int wy   = work / NX;                          // row-tile
    const int wx   = work - wy * NX;                     // N-tile (fastest: shares A)

    // decode (e, rt, row0, rowEnd) from counts
    int cnt[NEXP];
#pragma unroll
    for (int ee = 0; ee < NEXP; ++ee) cnt[ee] = counts[ee];
    int e = -1, rt = 0, row0 = 0, rowEnd = 0, rem = wy, off = 0;
#pragma unroll
    for (int ee = 0; ee < NEXP; ++ee) {
        const int nt = (cnt[ee] + 127) >> 7;
        if (e < 0 && rem < nt) { e = ee; rt = rem; row0 = off + rt * 128; rowEnd = off + cnt[ee]; }
        if (e < 0) rem -= nt;
        off += cnt[ee];
    }
    if (e < 0) return;   // wy >= ntiles

    const int nb = wx * 128;

    // double-buffered LDS: [2] x 128x32 bf16 for A and B  (32KB total)
    __shared__ __align__(16) bf16 As[2 * 128 * 32];
    __shared__ __align__(16) bf16 Bs[2 * 128 * 32];

    const int t = threadIdx.x;
    const int w = t >> 6, l = t & 63;      // 8 waves
    const int wm = w >> 1, wn = w & 1;     // 4x2 wave grid, 32x64 per wave

    // staging: wave w stages rows w*16 .. w*16+15 of A-tile and B-tile (1KB each)
    const int rA   = w * 16 + (l >> 2);
    // T2: pre-swizzled global k-slot for this lane's linear LDS dest
    const int colb = (((l & 3) ^ ((l >> 3) & 3)) * 8);

    int srow = row0 + rA; if (srow >= NSLOT) srow = NSLOT - 1;
    const bf16* aSrc;
    if (FIRST) aSrc = Adata + (size_t)slot_tok[srow] * KD + colb;
    else       aSrc = Adata + (size_t)srow * KD + colb;
    const bf16* bSrc = Bt + ((size_t)e * ND + nb + rA) * KD + colb;

    const int offW = w * 512;   // elem offset of this wave's 1KB chunk

    f32x4 acc[2][4] = {};
    const int lr = l & 15;
    // T2 read-side: phys slot = (l>>4) ^ ((lr>>1)&3)
    const int lks = (((l >> 4) ^ ((lr >> 1) & 3)) * 8);

    auto STAGE = [&](int buf, int k0) {
        gload16(aSrc + k0, As + buf * 4096 + offW);
        gload16(bSrc + k0, Bs + buf * 4096 + offW);
    };
    auto COMPUTE = [&](int buf) {
        const bf16* ab = As + buf * 4096;
        const bf16* bb = Bs + buf * 4096;
        bf16x8 aF[2], bF[4];
#pragma unroll
        for (int mi = 0; mi < 2; ++mi)
            aF[mi] = *(const bf16x8*)(ab + (wm * 32 + mi * 16 + lr) * 32 + lks);
#pragma unroll
        for (int nj = 0; nj < 4; ++nj)
            bF[nj] = *(const bf16x8*)(bb + (wn * 64 + nj * 16 + lr) * 32 + lks);
#pragma unroll
        for (int mi = 0; mi < 2; ++mi)
#pragma unroll
            for (int nj = 0; nj < 4; ++nj)
                acc[mi][nj] = __builtin_amdgcn_mfma_f32_16x16x32_bf16(
                    aF[mi], bF[nj], acc[mi][nj], 0, 0, 0);
    };

    // prologue: tile 0 staged and drained (compiler emits waits at the barrier)
    STAGE(0, 0);
    __syncthreads();

    int buf = 0;
    for (int t2 = 0; t2 < NT - 1; ++t2) {
        STAGE(buf ^ 1, (t2 + 1) * 32);   // issue next tile's loads first
        COMPUTE(buf);                     // ds_read + MFMA on current tile
        __syncthreads();                  // one barrier: drains loads, WAR-safe
        buf ^= 1;
    }
    COMPUTE(buf);                         // last tile (already drained)

    const int rowW = row0 + wm * 32;
    const int colW = nb + wn * 64;
#pragma unroll
    for (int mi = 0; mi < 2; ++mi) {
#pragma unroll
        for (int nj = 0; nj < 4; ++nj) {
#pragma unroll
            for (int r = 0; r < 4; ++r) {
                int row = rowW + mi * 16 + (l >> 4) * 4 + r;
                int col = colW + nj * 16 + lr;
                if (row < rowEnd) {
                    float v = acc[mi][nj][r] + bias[e * ND + col];
                    if (FIRST) v = fmaxf(v, 0.f);
                    Out[(size_t)row * ND + col] = (bf16)v;
                }
            }
        }
    }
}

// ---------------- combine: out[n] = w0*Y[slot0] + w1*Y[slot1] (bf16 Y) ----------
__global__ __launch_bounds__(256)
void combine_kernel(const bf16* __restrict__ Yg, const int* __restrict__ pos,
                    const float* __restrict__ slot_w, float* __restrict__ out)
{
    const int idx = blockIdx.x * 256 + threadIdx.x;  // over NTOK*DDIM/8
    const int n  = idx >> 6;                          // DDIM/8 = 64
    const int d8 = (idx & 63) * 8;
    const int s0 = pos[n * 2 + 0], s1 = pos[n * 2 + 1];
    const float w0 = slot_w[s0], w1 = slot_w[s1];
    bf16x8 a = *(const bf16x8*)(Yg + (size_t)s0 * DDIM + d8);
    bf16x8 b = *(const bf16x8*)(Yg + (size_t)s1 * DDIM + d8);
    float o[8];
#pragma unroll
    for (int j = 0; j < 8; ++j)
        o[j] = w0 * (float)a[j] + w1 * (float)b[j];
    float* op = out + (size_t)n * DDIM + d8;
    *(float4*)(op + 0) = make_float4(o[0], o[1], o[2], o[3]);
    *(float4*)(op + 4) = make_float4(o[4], o[5], o[6], o[7]);
}

extern "C" void kernel_launch(void* const* d_in, const int* in_sizes, int n_in,
                              void* d_out, int out_size, void* d_ws, size_t ws_size,
                              hipStream_t stream)
{
    (void)in_sizes; (void)n_in;
    const float* x  = (const float*)d_in[0];
    const float* Wg = (const float*)d_in[1];
    const float* bg = (const float*)d_in[2];
    const float* W1 = (const float*)d_in[3];
    const float* b1 = (const float*)d_in[4];
    const float* W2 = (const float*)d_in[5];
    const float* b2 = (const float*)d_in[6];
    float* out = (float*)d_out;

    uint8_t* ws = (uint8_t*)d_ws;
    size_t off = 0;
    auto alloc = [&](size_t bytes) -> void* {
        void* p = ws + off;
        off = (off + bytes + 255) & ~(size_t)255;
        return p;
    };
    bf16*  xb      = (bf16*)alloc((size_t)NTOK * DDIM * 2);
    bf16*  w1t     = (bf16*)alloc((size_t)NEXP * FDIM * DDIM * 2);  // [E][FF][D]
    bf16*  w2t     = (bf16*)alloc((size_t)NEXP * DDIM * FDIM * 2);  // [E][D][FF]
    bf16*  Hg      = (bf16*)alloc((size_t)NSLOT * FDIM * 2);
    bf16*  Yg      = (bf16*)alloc((size_t)NSLOT * DDIM * 2);
    int*   counts  = (int*)alloc(16 * 4);          // counts[0..7] + cursors[8..15]
    int*   cursors = counts + NEXP;                // same 64B memset covers both
    int*   top_idx = (int*)alloc((size_t)NTOK * 2 * 4);
    float* top_w   = (float*)alloc((size_t)NTOK * 2 * 4);
    int*   pos     = (int*)alloc((size_t)NTOK * 2 * 4);
    int*   slot_tok= (int*)alloc((size_t)NSLOT * 4);
    float* slot_w  = (float*)alloc((size_t)NSLOT * 4);

    if (ws_size < off) {
        // workspace too small: distinguishable failure signature (out = 0)
        hipMemsetAsync(d_out, 0, (size_t)out_size * 4, stream);
        return;
    }

    hipMemsetAsync(counts, 0, 16 * 4, stream);   // zero counts + cursors

    prep_kernel<<<5120, 256, 0, stream>>>(x, Wg, bg, xb, top_idx, top_w, counts,
                                          W1, w1t, W2, w2t);
    scatter_kernel<<<NTOK / 256, 256, 0, stream>>>(top_idx, top_w, counts, cursors,
                                                   slot_tok, slot_w, pos);

    moe_gemm<DDIM, FDIM, true><<<dim3(FDIM / 128, MAXTILES), 512, 0, stream>>>(
        xb, w1t, b1, Hg, slot_tok, counts);
    moe_gemm<FDIM, DDIM, false><<<dim3(DDIM / 128, MAXTILES), 512, 0, stream>>>(
        Hg, w2t, b2, Yg, slot_tok, counts);

    combine_kernel<<<(NTOK * DDIM / 8) / 256, 256, 0, stream>>>(Yg, pos, slot_w, out);
}